// Round 3
// baseline (2044.304 us; speedup 1.0000x reference)
//
#include <hip/hip_runtime.h>
#include <hip/hip_bf16.h>
#include <math.h>

#define TT 77
#define MTOT 32768

typedef __attribute__((ext_vector_type(8))) short bf16x8;
typedef __attribute__((ext_vector_type(4))) float floatx4;

#define GPTR(p) ((const __attribute__((address_space(1))) void*)(p))
#define LPTR(p) ((__attribute__((address_space(3))) void*)(p))

__device__ __forceinline__ float wred_sum(float v) {
#pragma unroll
  for (int o = 32; o >= 1; o >>= 1) v += __shfl_xor(v, o, 64);
  return v;
}

__device__ __forceinline__ unsigned short f2bf(float f) {
  unsigned int u = __float_as_uint(f);
  unsigned int r = (u + 0x7fffu + ((u >> 16) & 1u)) >> 16;
  return (unsigned short)r;
}
__device__ __forceinline__ float bf2f(unsigned short h) {
  return __uint_as_float(((unsigned int)h) << 16);
}

// ---------------- LayerNorm over rows of 512 -> bf16 out (one wave/row) -------
__global__ __launch_bounds__(256)
void ln_bf16_kernel(const float* __restrict__ in, const float* __restrict__ gw,
                    const float* __restrict__ gb, unsigned short* __restrict__ out) {
  const int wv = threadIdx.x >> 6, lane = threadIdx.x & 63;
  const size_t row = (size_t)blockIdx.x * 4 + wv;
  const float* p = in + row * 512 + lane * 8;
  float4 a = *(const float4*)p;
  float4 b = *(const float4*)(p + 4);
  float s = a.x + a.y + a.z + a.w + b.x + b.y + b.z + b.w;
  float mu = wred_sum(s) * (1.0f / 512.0f);
  float d[8] = {a.x - mu, a.y - mu, a.z - mu, a.w - mu,
                b.x - mu, b.y - mu, b.z - mu, b.w - mu};
  float ss = 0.f;
#pragma unroll
  for (int i = 0; i < 8; ++i) ss = fmaf(d[i], d[i], ss);
  float var = wred_sum(ss) * (1.0f / 512.0f);
  float rstd = rsqrtf(var + 1e-5f);
  float4 w0 = *(const float4*)(gw + lane * 8);
  float4 w1 = *(const float4*)(gw + lane * 8 + 4);
  float4 c0 = *(const float4*)(gb + lane * 8);
  float4 c1 = *(const float4*)(gb + lane * 8 + 4);
  float o[8];
  o[0] = d[0] * rstd * w0.x + c0.x;  o[1] = d[1] * rstd * w0.y + c0.y;
  o[2] = d[2] * rstd * w0.z + c0.z;  o[3] = d[3] * rstd * w0.w + c0.w;
  o[4] = d[4] * rstd * w1.x + c1.x;  o[5] = d[5] * rstd * w1.y + c1.y;
  o[6] = d[6] * rstd * w1.z + c1.z;  o[7] = d[7] * rstd * w1.w + c1.w;
  __align__(16) unsigned short ob[8];
#pragma unroll
  for (int i = 0; i < 8; ++i) ob[i] = f2bf(o[i]);
  *(uint4*)(out + row * 512 + lane * 8) = *(const uint4*)ob;
}

// ---------------- weight transpose + bf16 convert: W[K,N] -> WT[N,K] ----------
__global__ __launch_bounds__(256)
void transpose_bf16_kernel(const float* __restrict__ W, unsigned short* __restrict__ WTb,
                           int K, int N) {
  __shared__ float s[32][33];
  const int tx = threadIdx.x & 31, ty = threadIdx.x >> 5;  // ty 0..7
  const int n0 = blockIdx.x * 32, k0 = blockIdx.y * 32;
#pragma unroll
  for (int j = 0; j < 4; ++j)
    s[ty + 8 * j][tx] = W[(size_t)(k0 + ty + 8 * j) * N + n0 + tx];
  __syncthreads();
#pragma unroll
  for (int j = 0; j < 4; ++j)
    WTb[(size_t)(n0 + ty + 8 * j) * K + k0 + tx] = f2bf(s[tx][ty + 8 * j]);
}

// ---------------- text projections: k (l2-normed, head-major), v, pad ---------
__global__ __launch_bounds__(256)
void text_proj_kernel(const float* __restrict__ text,
                      const float* __restrict__ wk, const float* __restrict__ bk,
                      const float* __restrict__ wv, const float* __restrict__ bv,
                      float* __restrict__ kh,   // [B,8,77,64] head-major
                      float* __restrict__ vf,   // [616,512]
                      float* __restrict__ pad) {
  __shared__ float st[512];
  __shared__ float red[8];
  const int tid = threadIdx.x;
  const int row = blockIdx.x;          // b*77 + t
  const int b = row / 77, t = row - b * 77;
  const int wvid = tid >> 6, lane = tid & 63;
  float t0 = text[(size_t)row * 512 + tid];
  float t1 = text[(size_t)row * 512 + tid + 256];
  st[tid] = t0;
  st[tid + 256] = t1;
  float ab = wred_sum(fabsf(t0) + fabsf(t1));
  if (lane == 0) red[wvid] = ab;
  __syncthreads();
  const int c0 = tid, c1 = tid + 256;
  float ak0 = bk[c0], ak1 = bk[c1];
  float av0 = bv[c0], av1 = bv[c1];
  for (int kk = 0; kk < 512; ++kk) {
    float tv = st[kk];
    ak0 = fmaf(tv, wk[(size_t)kk * 512 + c0], ak0);
    ak1 = fmaf(tv, wk[(size_t)kk * 512 + c1], ak1);
    av0 = fmaf(tv, wv[(size_t)kk * 512 + c0], av0);
    av1 = fmaf(tv, wv[(size_t)kk * 512 + c1], av1);
  }
  float ss = wred_sum(ak0 * ak0 + ak1 * ak1);
  if (lane == 0) red[4 + wvid] = ss;
  __syncthreads();
  float padsum = red[0] + red[1] + red[2] + red[3];
  float sstot = red[4] + red[5] + red[6] + red[7];
  float sc = 1.0f / fmaxf(sqrtf(sstot), 1e-6f);
  const int h0 = c0 >> 6, d0 = c0 & 63;
  const int h1 = c1 >> 6, d1 = c1 & 63;
  kh[(((size_t)b * 8 + h0) * 77 + t) * 64 + d0] = ak0 * sc;
  kh[(((size_t)b * 8 + h1) * 77 + t) * 64 + d1] = ak1 * sc;
  vf[(size_t)row * 512 + c0] = av0;
  vf[(size_t)row * 512 + c1] = av1;
  if (tid == 0) pad[row] = (padsum <= 1e-6f) ? 1.0f : 0.0f;
}

// ---------------- fused attention v3: one wave per row ------------------------
__device__ __forceinline__ void top3_insert(float v, float& a, float& b, float& c) {
  if (v > a) { c = b; b = a; a = v; }
  else if (v > b) { c = b; b = v; }
  else if (v > c) { c = v; }
}

__global__ __launch_bounds__(256)
void attn_kernel(const float* __restrict__ q,    // [32768,512] fp32 UN-normalized
                 const float* __restrict__ kh,   // [B,8,77,64] head-major l2-normed
                 const float* __restrict__ vf,   // [616,512]
                 const float* __restrict__ pad,  // [616]
                 const float* __restrict__ logit_scale,
                 unsigned short* __restrict__ alignedb,  // [32768,512] bf16
                 float* __restrict__ conf_out) {         // [32768]
  __shared__ __align__(16) float s_q[4][512];
  __shared__ float s_lw[4][8][80];
  __shared__ short s_lt[4][8][80];
  __shared__ int s_cnt[4][8];
  const int tid = threadIdx.x;
  const int wv = tid >> 6, lane = tid & 63;
  const int row = blockIdx.x * 4 + wv;
  const int b = row >> 12;
  const float ls = fminf(fmaxf(logit_scale[0], -2.0f), 2.0f);
  const float scale = expf(ls) * 0.125f;

  // ---- load q row + fused L2 normalize -> LDS ----
  {
    const float* qp = q + (size_t)row * 512 + lane * 8;
    float4 a = *(const float4*)qp;
    float4 c = *(const float4*)(qp + 4);
    float ss = a.x * a.x + a.y * a.y + a.z * a.z + a.w * a.w +
               c.x * c.x + c.y * c.y + c.z * c.z + c.w * c.w;
    ss = wred_sum(ss);
    const float nsc = 1.0f / fmaxf(sqrtf(ss), 1e-6f);
    a.x *= nsc; a.y *= nsc; a.z *= nsc; a.w *= nsc;
    c.x *= nsc; c.y *= nsc; c.z *= nsc; c.w *= nsc;
    *(float4*)(&s_q[wv][lane * 8]) = a;
    *(float4*)(&s_q[wv][lane * 8 + 4]) = c;
  }
  __syncthreads();

  // pad flags for this lane's t values
  const float pad0 = pad[b * 77 + lane];
  const float pad1 = (lane < 13) ? pad[b * 77 + 64 + lane] : 1.0f;
  const unsigned long long lmask = (1ull << lane) - 1ull;

  float cm = 0.f;  // sum of per-head conf
#pragma unroll
  for (int h = 0; h < 8; ++h) {
    const float* khh = kh + ((size_t)(b * 8 + h) * 77) * 64;
    // ---- sim for t = lane ----
    float acc0 = 0.f;
    {
      const float* kp = khh + (size_t)lane * 64;
#pragma unroll
      for (int j = 0; j < 8; ++j) {
        float4 kv0 = *(const float4*)(kp + j * 8);
        float4 kv1 = *(const float4*)(kp + j * 8 + 4);
        float4 qv0 = *(const float4*)(&s_q[wv][h * 64 + j * 8]);
        float4 qv1 = *(const float4*)(&s_q[wv][h * 64 + j * 8 + 4]);
        acc0 = fmaf(kv0.x, qv0.x, acc0); acc0 = fmaf(kv0.y, qv0.y, acc0);
        acc0 = fmaf(kv0.z, qv0.z, acc0); acc0 = fmaf(kv0.w, qv0.w, acc0);
        acc0 = fmaf(kv1.x, qv1.x, acc0); acc0 = fmaf(kv1.y, qv1.y, acc0);
        acc0 = fmaf(kv1.z, qv1.z, acc0); acc0 = fmaf(kv1.w, qv1.w, acc0);
      }
    }
    const float v0 = (pad0 != 0.0f) ? -INFINITY : acc0 * scale;
    // ---- sim for t = 64 + lane (13 lanes) ----
    float v1 = -INFINITY;
    if (lane < 13 && pad1 == 0.0f) {
      const float* kp = khh + (size_t)(64 + lane) * 64;
      float acc1 = 0.f;
#pragma unroll
      for (int j = 0; j < 8; ++j) {
        float4 kv0 = *(const float4*)(kp + j * 8);
        float4 kv1 = *(const float4*)(kp + j * 8 + 4);
        float4 qv0 = *(const float4*)(&s_q[wv][h * 64 + j * 8]);
        float4 qv1 = *(const float4*)(&s_q[wv][h * 64 + j * 8 + 4]);
        acc1 = fmaf(kv0.x, qv0.x, acc1); acc1 = fmaf(kv0.y, qv0.y, acc1);
        acc1 = fmaf(kv0.z, qv0.z, acc1); acc1 = fmaf(kv0.w, qv0.w, acc1);
        acc1 = fmaf(kv1.x, qv1.x, acc1); acc1 = fmaf(kv1.y, qv1.y, acc1);
        acc1 = fmaf(kv1.z, qv1.z, acc1); acc1 = fmaf(kv1.w, qv1.w, acc1);
      }
      v1 = acc1 * scale;
    }
    // ---- wave top3 (tie-exact) ----
    float a = -INFINITY, bt = -INFINITY, c = -INFINITY;
    top3_insert(v0, a, bt, c);
    top3_insert(v1, a, bt, c);
#pragma unroll
    for (int s = 32; s >= 1; s >>= 1) {
      float oa = __shfl_xor(a, s, 64);
      float ob = __shfl_xor(bt, s, 64);
      float oc = __shfl_xor(c, s, 64);
      top3_insert(oa, a, bt, c);
      top3_insert(ob, a, bt, c);
      top3_insert(oc, a, bt, c);
    }
    const float thr = c, m1 = a;
    // ---- softmax over surviving entries + entropy pieces ----
    float ev0 = 0.f, ev1 = 0.f;
    float s0 = 0.f, s1 = 0.f, cnt = 0.f;
    if (v0 >= thr) {
      float e = expf(v0 - m1);
      if (e > 0.f) { ev0 = e; s0 += e; s1 += e * (v0 - m1); cnt += 1.f; }
    }
    if (v1 >= thr) {
      float e = expf(v1 - m1);
      if (e > 0.f) { ev1 = e; s0 += e; s1 += e * (v1 - m1); cnt += 1.f; }
    }
    s0 = wred_sum(s0);
    s1 = wred_sum(s1);
    cnt = wred_sum(cnt);
    float attn0 = 0.f, attn1 = 0.f, conf_h = 0.f;
    if (cnt > 0.f) {
      const float inv = 1.0f / s0;
      attn0 = ev0 * inv;
      attn1 = ev1 * inv;
      const float maxp = inv;
      const float teff = fmaxf(cnt, 2.0f);
      float entn = (logf(s0) - s1 * inv) + (77.0f - cnt) * 1.8420681e-7f;
      const float ent = fmaxf(entn / logf(teff), 0.0f);
      conf_h = fminf(fmaxf(maxp * (1.0f - ent), 0.0f), 1.0f);
    }
    cm += conf_h;
    // ---- ballot-compact sparse weights to LDS ----
    unsigned long long m0 = __ballot(attn0 != 0.0f);
    unsigned long long m1b = __ballot(attn1 != 0.0f);
    const int c0n = __popcll(m0);
    if (attn0 != 0.0f) {
      const int rk = __popcll(m0 & lmask);
      s_lt[wv][h][rk] = (short)lane;
      s_lw[wv][h][rk] = attn0;
    }
    if (attn1 != 0.0f) {
      const int rk = c0n + __popcll(m1b & lmask);
      s_lt[wv][h][rk] = (short)(64 + lane);
      s_lw[wv][h][rk] = attn1;
    }
    if (lane == 0) s_cnt[wv][h] = c0n + __popcll(m1b);
  }
  if (lane == 0) {
    cm *= 0.125f;
    cm = fminf(fmaxf(cm, 0.0f), 1.0f);
    conf_out[row] = 0.35f + 0.65f * cm;
  }
  __syncthreads();
  // ---- sparse PV: lane owns 8 contiguous channels of head h = lane>>3 ----
  {
    const int h = lane >> 3;
    const int cnt = s_cnt[wv][h];
    float acc[8] = {0.f, 0.f, 0.f, 0.f, 0.f, 0.f, 0.f, 0.f};
    for (int i = 0; i < cnt; ++i) {
      const int t = s_lt[wv][h][i];
      const float w = s_lw[wv][h][i];
      const float* vp = vf + (size_t)(b * 77 + t) * 512 + lane * 8;
      float4 va = *(const float4*)vp;
      float4 vb2 = *(const float4*)(vp + 4);
      acc[0] = fmaf(w, va.x, acc[0]);  acc[1] = fmaf(w, va.y, acc[1]);
      acc[2] = fmaf(w, va.z, acc[2]);  acc[3] = fmaf(w, va.w, acc[3]);
      acc[4] = fmaf(w, vb2.x, acc[4]); acc[5] = fmaf(w, vb2.y, acc[5]);
      acc[6] = fmaf(w, vb2.z, acc[6]); acc[7] = fmaf(w, vb2.w, acc[7]);
    }
    __align__(16) unsigned short ob[8];
#pragma unroll
    for (int i = 0; i < 8; ++i) ob[i] = f2bf(acc[i]);
    *(uint4*)(alignedb + (size_t)row * 512 + lane * 8) = *(const uint4*)ob;
  }
}

// ---------------- bf16 MFMA GEMM: out = epi(A[M,K] @ WT[N,K]^T + bias) --------
// EPI 0: +bias -> fp32
// EPI 1: (.)*e1f[row] -> fp32                         (wo * conf)
// EPI 2: bf2f(e0b[r,c]) + scf*sigmoid(.)*clip(e2f[r],.3,1)*e1f[r,c] -> fp32 (y)
// EPI 3: gelu(.) -> bf16
// EPI 4: e1f[r,c] + . -> fp32                         (ffn2 + residual)
template <int EPI>
__global__ __launch_bounds__(256)
void mfma_gemm(const unsigned short* __restrict__ A,
               const unsigned short* __restrict__ WT,
               const float* __restrict__ bias,
               void* __restrict__ outv, int M, int N, int K,
               const unsigned short* __restrict__ e0b,
               const float* __restrict__ e1f,
               const float* __restrict__ e2f,
               const float* __restrict__ scf) {
  __shared__ __align__(16) unsigned short As[128 * 32];
  __shared__ __align__(16) unsigned short Bs[128 * 32];
  const int tid = threadIdx.x;
  const int wid = tid >> 6, lane = tid & 63;
  const int wr = wid >> 1, wc = wid & 1;
  const int m16 = lane & 15, quad = lane >> 4;
  const int row0 = blockIdx.y * 128, col0 = blockIdx.x * 128;

  const floatx4 zero4 = {0.f, 0.f, 0.f, 0.f};
  floatx4 acc[4][4];
#pragma unroll
  for (int i = 0; i < 4; ++i)
#pragma unroll
    for (int j = 0; j < 4; ++j) acc[i][j] = zero4;

  const unsigned short* Ag = A + (size_t)(row0 + (tid >> 2)) * K + (tid & 3) * 8;
  const unsigned short* Bg = WT + (size_t)(col0 + (tid >> 2)) * K + (tid & 3) * 8;
  char* AsB = (char*)As + tid * 16;
  char* BsB = (char*)Bs + tid * 16;
  const unsigned short* aP = As + (wr * 64 + m16) * 32 + quad * 8;
  const unsigned short* bP = Bs + (wc * 64 + m16) * 32 + quad * 8;

  for (int k0 = 0; k0 < K; k0 += 32) {
    __syncthreads();
    __builtin_amdgcn_global_load_lds(GPTR(Ag + k0), LPTR(AsB), 16, 0, 0);
    __builtin_amdgcn_global_load_lds(GPTR(Ag + (size_t)64 * K + k0), LPTR(AsB + 4096), 16, 0, 0);
    __builtin_amdgcn_global_load_lds(GPTR(Bg + k0), LPTR(BsB), 16, 0, 0);
    __builtin_amdgcn_global_load_lds(GPTR(Bg + (size_t)64 * K + k0), LPTR(BsB + 4096), 16, 0, 0);
    __syncthreads();
    bf16x8 af[4], bfr[4];
#pragma unroll
    for (int i = 0; i < 4; ++i) {
      af[i] = *(const bf16x8*)(aP + i * 16 * 32);
      bfr[i] = *(const bf16x8*)(bP + i * 16 * 32);
    }
#pragma unroll
    for (int mi = 0; mi < 4; ++mi)
#pragma unroll
      for (int ni = 0; ni < 4; ++ni)
        acc[mi][ni] = __builtin_amdgcn_mfma_f32_16x16x32_bf16(af[mi], bfr[ni], acc[mi][ni], 0, 0, 0);
  }

  float* outf = (float*)outv;
  unsigned short* outb = (unsigned short*)outv;
  float bb[4];
#pragma unroll
  for (int ni = 0; ni < 4; ++ni) bb[ni] = bias[col0 + wc * 64 + ni * 16 + m16];
  const float alphav = (EPI == 2) ? scf[0] : 0.f;

#pragma unroll
  for (int mi = 0; mi < 4; ++mi) {
#pragma unroll
    for (int r = 0; r < 4; ++r) {
      const int row = row0 + wr * 64 + mi * 16 + quad * 4 + r;
      float rowscale = 1.f, geo = 0.f;
      if (EPI == 1) rowscale = e1f[row];
      if (EPI == 2) geo = fminf(fmaxf(e2f[row], 0.3f), 1.0f);
#pragma unroll
      for (int ni = 0; ni < 4; ++ni) {
        const int col = col0 + wc * 64 + ni * 16 + m16;
        const size_t idx = (size_t)row * N + col;
        float o = acc[mi][ni][r] + bb[ni];
        if (EPI == 0) {
          outf[idx] = o;
        } else if (EPI == 1) {
          outf[idx] = o * rowscale;
        } else if (EPI == 2) {
          const float x = bf2f(e0b[idx]);
          const float al = e1f[idx];
          const float sg = 1.0f / (1.0f + expf(-o));
          outf[idx] = x + alphav * sg * geo * al;
        } else if (EPI == 3) {
          const float g = 0.5f * o * (1.0f + erff(o * 0.70710678118654752f));
          outb[idx] = f2bf(g);
        } else {
          outf[idx] = o + e1f[idx];
        }
      }
    }
  }
}

extern "C" void kernel_launch(void* const* d_in, const int* in_sizes, int n_in,
                              void* d_out, int out_size, void* d_ws, size_t ws_size,
                              hipStream_t stream) {
  const float* visual = (const float*)d_in[0];
  const float* text   = (const float*)d_in[1];
  const float* geo    = (const float*)d_in[2];
  const float* ln1_w  = (const float*)d_in[3];
  const float* ln1_b  = (const float*)d_in[4];
  const float* wq     = (const float*)d_in[5];
  const float* bq     = (const float*)d_in[6];
  const float* wk     = (const float*)d_in[7];
  const float* bk     = (const float*)d_in[8];
  const float* wvw    = (const float*)d_in[9];
  const float* bv     = (const float*)d_in[10];
  const float* wo     = (const float*)d_in[11];
  const float* bo     = (const float*)d_in[12];
  const float* gate_w = (const float*)d_in[13];
  const float* gate_b = (const float*)d_in[14];
  const float* logit_scale = (const float*)d_in[15];
  const float* alpha  = (const float*)d_in[16];
  const float* ln2_w  = (const float*)d_in[17];
  const float* ln2_b  = (const float*)d_in[18];
  const float* ffn_w1 = (const float*)d_in[19];
  const float* ffn_b1 = (const float*)d_in[20];
  const float* ffn_w2 = (const float*)d_in[21];
  const float* ffn_b2 = (const float*)d_in[22];
  float* out = (float*)d_out;

  char* ws = (char*)d_ws;
  float* BUF1          = (float*)ws;                          // 64 MB: q -> alignedO -> GCH(bf16)
  float* BUF2          = (float*)(ws + 67108864);             // 64 MB: y
  unsigned short* Xb   = (unsigned short*)(ws + 134217728);   // 32 MB: x bf16 -> h bf16
  unsigned short* ALb  = (unsigned short*)(ws + 167772160);   // 32 MB: aligned bf16
  unsigned short* wqT  = (unsigned short*)(ws + 201326592);
  unsigned short* woT  = wqT + 262144;
  unsigned short* gateT = woT + 262144;
  unsigned short* w1T  = gateT + 262144;                      // [2048,512]
  unsigned short* w2T  = w1T + 1048576;                       // [512,2048]
  float* KH   = (float*)(ws + 207093760);                     // [8,8,77,64]
  float* VF   = (float*)(ws + 208355328);                     // [616,512]
  float* PAD  = (float*)(ws + 209616896);
  float* CONF = (float*)(ws + 209619360);

  // weight transposes -> bf16 [N,K]
  transpose_bf16_kernel<<<dim3(16, 16), 256, 0, stream>>>(wq, wqT, 512, 512);
  transpose_bf16_kernel<<<dim3(16, 16), 256, 0, stream>>>(wo, woT, 512, 512);
  transpose_bf16_kernel<<<dim3(16, 16), 256, 0, stream>>>(gate_w, gateT, 512, 512);
  transpose_bf16_kernel<<<dim3(64, 16), 256, 0, stream>>>(ffn_w1, w1T, 512, 2048);
  transpose_bf16_kernel<<<dim3(16, 64), 256, 0, stream>>>(ffn_w2, w2T, 2048, 512);

  // 1. x = LN1(visual) -> bf16
  ln_bf16_kernel<<<MTOT / 4, 256, 0, stream>>>(visual, ln1_w, ln1_b, Xb);
  // 2. text projections
  text_proj_kernel<<<8 * TT, 256, 0, stream>>>(text, wk, bk, wvw, bv, KH, VF, PAD);
  // 3. q = x @ wq + bq (fp32 out, un-normalized; attn fuses the L2 norm)
  mfma_gemm<0><<<dim3(4, 256), 256, 0, stream>>>(Xb, wqT, bq, BUF1, MTOT, 512, 512,
                                                 nullptr, nullptr, nullptr, nullptr);
  // 4. attention (wave-per-row) -> ALb (bf16), CONF
  attn_kernel<<<MTOT / 4, 256, 0, stream>>>(BUF1, KH, VF, PAD, logit_scale, ALb, CONF);
  // 5. alignedO = (aligned @ wo + bo) * conf -> BUF1 fp32
  mfma_gemm<1><<<dim3(4, 256), 256, 0, stream>>>(ALb, woT, bo, BUF1, MTOT, 512, 512,
                                                 nullptr, CONF, nullptr, nullptr);
  // 6. y = x + alpha*sigmoid(x@gate_w+gate_b)*geo*alignedO -> BUF2 fp32
  mfma_gemm<2><<<dim3(4, 256), 256, 0, stream>>>(Xb, gateT, gate_b, BUF2, MTOT, 512, 512,
                                                 Xb, BUF1, geo, alpha);
  // 7. h = LN2(y) -> Xb (bf16)
  ln_bf16_kernel<<<MTOT / 4, 256, 0, stream>>>(BUF2, ln2_w, ln2_b, Xb);
  // 8. FFN in 2 chunks of 16384 rows; GCH (bf16) overlays BUF1
  unsigned short* GCH = (unsigned short*)BUF1;
  for (int ch = 0; ch < 2; ++ch) {
    const size_t off = (size_t)ch * 16384;
    mfma_gemm<3><<<dim3(16, 128), 256, 0, stream>>>(Xb + off * 512, w1T, ffn_b1, GCH,
                                                    16384, 2048, 512,
                                                    nullptr, nullptr, nullptr, nullptr);
    mfma_gemm<4><<<dim3(4, 128), 256, 0, stream>>>(GCH, w2T, ffn_b2, out + off * 512,
                                                   16384, 512, 2048,
                                                   nullptr, BUF2 + off * 512, nullptr, nullptr);
  }
}

// Round 4
// 806.000 us; speedup vs baseline: 2.5364x; 2.5364x over previous
//
#include <hip/hip_runtime.h>
#include <hip/hip_bf16.h>
#include <math.h>

#define TT 77
#define MTOT 32768

typedef __attribute__((ext_vector_type(8))) short bf16x8;
typedef __attribute__((ext_vector_type(4))) float floatx4;

#define GPTR(p) ((const __attribute__((address_space(1))) void*)(p))
#define LPTR(p) ((__attribute__((address_space(3))) void*)(p))

__device__ __forceinline__ float wred_sum(float v) {
#pragma unroll
  for (int o = 32; o >= 1; o >>= 1) v += __shfl_xor(v, o, 64);
  return v;
}
__device__ __forceinline__ float wred_max(float v) {
#pragma unroll
  for (int o = 32; o >= 1; o >>= 1) v = fmaxf(v, __shfl_xor(v, o, 64));
  return v;
}

__device__ __forceinline__ unsigned short f2bf(float f) {
  unsigned int u = __float_as_uint(f);
  unsigned int r = (u + 0x7fffu + ((u >> 16) & 1u)) >> 16;
  return (unsigned short)r;
}
__device__ __forceinline__ float bf2f(unsigned short h) {
  return __uint_as_float(((unsigned int)h) << 16);
}

// ---------------- LayerNorm over rows of 512 -> bf16 out (one wave per row) ---
__global__ __launch_bounds__(256)
void ln_bf16_kernel(const float* __restrict__ in, const float* __restrict__ gw,
                    const float* __restrict__ gb, unsigned short* __restrict__ out) {
  const int wv = threadIdx.x >> 6, lane = threadIdx.x & 63;
  const size_t row = (size_t)blockIdx.x * 4 + wv;
  const float* p = in + row * 512 + lane * 8;
  float4 a = *(const float4*)p;
  float4 b = *(const float4*)(p + 4);
  float s = a.x + a.y + a.z + a.w + b.x + b.y + b.z + b.w;
  float mu = wred_sum(s) * (1.0f / 512.0f);
  float d[8] = {a.x - mu, a.y - mu, a.z - mu, a.w - mu,
                b.x - mu, b.y - mu, b.z - mu, b.w - mu};
  float ss = 0.f;
#pragma unroll
  for (int i = 0; i < 8; ++i) ss = fmaf(d[i], d[i], ss);
  float var = wred_sum(ss) * (1.0f / 512.0f);
  float rstd = rsqrtf(var + 1e-5f);
  float4 w0 = *(const float4*)(gw + lane * 8);
  float4 w1 = *(const float4*)(gw + lane * 8 + 4);
  float4 c0 = *(const float4*)(gb + lane * 8);
  float4 c1 = *(const float4*)(gb + lane * 8 + 4);
  float o[8];
  o[0] = d[0] * rstd * w0.x + c0.x;  o[1] = d[1] * rstd * w0.y + c0.y;
  o[2] = d[2] * rstd * w0.z + c0.z;  o[3] = d[3] * rstd * w0.w + c0.w;
  o[4] = d[4] * rstd * w1.x + c1.x;  o[5] = d[5] * rstd * w1.y + c1.y;
  o[6] = d[6] * rstd * w1.z + c1.z;  o[7] = d[7] * rstd * w1.w + c1.w;
  __align__(16) unsigned short ob[8];
#pragma unroll
  for (int i = 0; i < 8; ++i) ob[i] = f2bf(o[i]);
  *(uint4*)(out + row * 512 + lane * 8) = *(const uint4*)ob;
}

// ---------------- q row: L2-normalize + fold sim scale + bf16 ------------------
__global__ __launch_bounds__(256)
void qnorm_kernel(const float* __restrict__ q, const float* __restrict__ logit_scale,
                  unsigned short* __restrict__ qnb) {
  const int wv = threadIdx.x >> 6, lane = threadIdx.x & 63;
  const size_t row = (size_t)blockIdx.x * 4 + wv;
  const float ls = fminf(fmaxf(logit_scale[0], -2.0f), 2.0f);
  const float scale = expf(ls) * 0.125f;
  const float* p = q + row * 512 + lane * 8;
  float4 a = *(const float4*)p;
  float4 b = *(const float4*)(p + 4);
  float ss = a.x * a.x + a.y * a.y + a.z * a.z + a.w * a.w +
             b.x * b.x + b.y * b.y + b.z * b.z + b.w * b.w;
  ss = wred_sum(ss);
  const float nsc = scale / fmaxf(sqrtf(ss), 1e-6f);
  float o[8] = {a.x * nsc, a.y * nsc, a.z * nsc, a.w * nsc,
                b.x * nsc, b.y * nsc, b.z * nsc, b.w * nsc};
  __align__(16) unsigned short ob[8];
#pragma unroll
  for (int i = 0; i < 8; ++i) ob[i] = f2bf(o[i]);
  *(uint4*)(qnb + row * 512 + lane * 8) = *(const uint4*)ob;
}

// ---------------- weight transpose + bf16 convert: W[K,N] -> WT[N,K] ----------
__global__ __launch_bounds__(256)
void transpose_bf16_kernel(const float* __restrict__ W, unsigned short* __restrict__ WTb,
                           int K, int N) {
  __shared__ float s[32][33];
  const int tx = threadIdx.x & 31, ty = threadIdx.x >> 5;  // ty 0..7
  const int n0 = blockIdx.x * 32, k0 = blockIdx.y * 32;
#pragma unroll
  for (int j = 0; j < 4; ++j)
    s[ty + 8 * j][tx] = W[(size_t)(k0 + ty + 8 * j) * N + n0 + tx];
  __syncthreads();
#pragma unroll
  for (int j = 0; j < 4; ++j)
    WTb[(size_t)(n0 + ty + 8 * j) * K + k0 + tx] = f2bf(s[tx][ty + 8 * j]);
}

// ---------------- text projections: k (l2-normed, bf16, head-major), v, pad ---
__global__ __launch_bounds__(256)
void text_proj_kernel(const float* __restrict__ text,
                      const float* __restrict__ wk, const float* __restrict__ bk,
                      const float* __restrict__ wv, const float* __restrict__ bv,
                      unsigned short* __restrict__ khb,  // [B,8,80,64] bf16
                      float* __restrict__ vf,            // [616,512]
                      float* __restrict__ pad) {
  __shared__ float st[512];
  __shared__ float red[8];
  const int tid = threadIdx.x;
  const int row = blockIdx.x;          // b*77 + t
  const int b = row / 77, t = row - b * 77;
  const int wvid = tid >> 6, lane = tid & 63;
  float t0 = text[(size_t)row * 512 + tid];
  float t1 = text[(size_t)row * 512 + tid + 256];
  st[tid] = t0;
  st[tid + 256] = t1;
  float ab = wred_sum(fabsf(t0) + fabsf(t1));
  if (lane == 0) red[wvid] = ab;
  __syncthreads();
  const int c0 = tid, c1 = tid + 256;
  float ak0 = bk[c0], ak1 = bk[c1];
  float av0 = bv[c0], av1 = bv[c1];
  for (int kk = 0; kk < 512; ++kk) {
    float tv = st[kk];
    ak0 = fmaf(tv, wk[(size_t)kk * 512 + c0], ak0);
    ak1 = fmaf(tv, wk[(size_t)kk * 512 + c1], ak1);
    av0 = fmaf(tv, wv[(size_t)kk * 512 + c0], av0);
    av1 = fmaf(tv, wv[(size_t)kk * 512 + c1], av1);
  }
  float ss = wred_sum(ak0 * ak0 + ak1 * ak1);
  if (lane == 0) red[4 + wvid] = ss;
  __syncthreads();
  float padsum = red[0] + red[1] + red[2] + red[3];
  float sstot = red[4] + red[5] + red[6] + red[7];
  float sc = 1.0f / fmaxf(sqrtf(sstot), 1e-6f);
  const int h0 = c0 >> 6, d0 = c0 & 63;
  const int h1 = c1 >> 6, d1 = c1 & 63;
  khb[(((size_t)b * 8 + h0) * 80 + t) * 64 + d0] = f2bf(ak0 * sc);
  khb[(((size_t)b * 8 + h1) * 80 + t) * 64 + d1] = f2bf(ak1 * sc);
  vf[(size_t)row * 512 + c0] = av0;
  vf[(size_t)row * 512 + c1] = av1;
  if (tid == 0) pad[row] = (padsum <= 1e-6f) ? 1.0f : 0.0f;
}

// ---------------- zero the k pad rows (t = 77..79) so sims there are finite ---
__global__ __launch_bounds__(256)
void kpad_zero_kernel(unsigned short* __restrict__ khb) {
  // 64 (b,h) * 3 rows * 64 ch = 12288 elements
  const int i = blockIdx.x * 256 + threadIdx.x;
  const int bh = i / 192, rem = i - bh * 192;
  const int t = 77 + rem / 64, d = rem & 63;
  khb[(((size_t)bh) * 80 + t) * 64 + d] = 0;
}

// ---------------- sims via MFMA: SIM[b,h,n,80] = qn . k^T ----------------------
__global__ __launch_bounds__(256)
void sim_kernel(const unsigned short* __restrict__ qnb,   // [32768,512] bf16 scaled
                const unsigned short* __restrict__ khb,   // [64,80,64] bf16
                float* __restrict__ SIM) {                // [64,4096,80] fp32
  __shared__ __align__(16) unsigned short As[128 * 72];
  __shared__ __align__(16) unsigned short Bs[80 * 72];
  const int bh = blockIdx.y;           // b*8+h
  const int b = bh >> 3, h = bh & 7;
  const int row0 = blockIdx.x * 128;   // within 4096
  const int tid = threadIdx.x;
  // stage A: 128 rows x 64 bf16 (2 threads per row, 64B each)
  {
    const int r = tid >> 1, half = tid & 1;
    const unsigned short* src = qnb + ((size_t)b * 4096 + row0 + r) * 512 + h * 64 + half * 32;
    unsigned short* dst = As + r * 72 + half * 32;
    *(uint4*)dst = *(const uint4*)src;
    *(uint4*)(dst + 8) = *(const uint4*)(src + 8);
    *(uint4*)(dst + 16) = *(const uint4*)(src + 16);
    *(uint4*)(dst + 24) = *(const uint4*)(src + 24);
  }
  // stage B: 80 rows x 64 bf16
  if (tid < 160) {
    const int r = tid >> 1, half = tid & 1;
    const unsigned short* src = khb + ((size_t)bh * 80 + r) * 64 + half * 32;
    unsigned short* dst = Bs + r * 72 + half * 32;
    *(uint4*)dst = *(const uint4*)src;
    *(uint4*)(dst + 8) = *(const uint4*)(src + 8);
    *(uint4*)(dst + 16) = *(const uint4*)(src + 16);
    *(uint4*)(dst + 24) = *(const uint4*)(src + 24);
  }
  __syncthreads();
  const int w = tid >> 6, lane = tid & 63;
  const int m16 = lane & 15, quad = lane >> 4;
  const unsigned short* aBase = As + (w * 32 + m16) * 72 + quad * 8;
  const unsigned short* bBase = Bs + m16 * 72 + quad * 8;
  bf16x8 af[2][2], bf[5][2];
#pragma unroll
  for (int mi = 0; mi < 2; ++mi)
#pragma unroll
    for (int kk = 0; kk < 2; ++kk)
      af[mi][kk] = *(const bf16x8*)(aBase + mi * 16 * 72 + kk * 32);
#pragma unroll
  for (int ni = 0; ni < 5; ++ni)
#pragma unroll
    for (int kk = 0; kk < 2; ++kk)
      bf[ni][kk] = *(const bf16x8*)(bBase + ni * 16 * 72 + kk * 32);
  const floatx4 zero4 = {0.f, 0.f, 0.f, 0.f};
  floatx4 acc[2][5];
#pragma unroll
  for (int mi = 0; mi < 2; ++mi)
#pragma unroll
    for (int ni = 0; ni < 5; ++ni) acc[mi][ni] = zero4;
#pragma unroll
  for (int kk = 0; kk < 2; ++kk)
#pragma unroll
    for (int mi = 0; mi < 2; ++mi)
#pragma unroll
      for (int ni = 0; ni < 5; ++ni)
        acc[mi][ni] = __builtin_amdgcn_mfma_f32_16x16x32_bf16(af[mi][kk], bf[ni][kk], acc[mi][ni], 0, 0, 0);
  float* obase = SIM + ((size_t)bh * 4096 + row0 + w * 32 + quad * 4) * 80 + m16;
#pragma unroll
  for (int mi = 0; mi < 2; ++mi)
#pragma unroll
    for (int ni = 0; ni < 5; ++ni)
#pragma unroll
      for (int r = 0; r < 4; ++r)
        obase[(size_t)(mi * 16 + r) * 80 + ni * 16] = acc[mi][ni][r];
}

// ---------------- topk + softmax + conf + sparse PV ---------------------------
__global__ __launch_bounds__(256)
void attn_pv_kernel(const float* __restrict__ SIM,   // [64,4096,80]
                    const float* __restrict__ vf,    // [616,512]
                    const float* __restrict__ pad,   // [616]
                    unsigned short* __restrict__ alignedb,  // [32768,512] bf16
                    float* __restrict__ conf_out) {         // [32768]
  __shared__ float s_lw[4][2][80];
  __shared__ short s_lt[4][2][80];
  __shared__ int s_cnt[4][2];
  __shared__ float s_conf[8];
  const int row = blockIdx.x;     // 0..32767
  const int b = row >> 12, n = row & 4095;
  const int tid = threadIdx.x, wv = tid >> 6, lane = tid & 63;
  const unsigned long long lmask = (1ull << lane) - 1ull;
  const float pad0 = pad[b * 77 + lane];
  const float pad1 = (lane < 13) ? pad[b * 77 + 64 + lane] : 1.0f;
#pragma unroll
  for (int hh = 0; hh < 2; ++hh) {
    const int h = wv * 2 + hh;
    const float* sp = SIM + ((size_t)(b * 8 + h) * 4096 + n) * 80;
    const float v0 = (pad0 != 0.0f) ? -INFINITY : sp[lane];
    const float v1 = (lane < 13 && pad1 == 0.0f) ? sp[64 + lane] : -INFINITY;
    // ---- 3-round max + count -> exact 3rd-largest threshold (ties kept) ----
    const float m1 = wred_max(fmaxf(v0, v1));
    const int c1 = __popcll(__ballot(v0 == m1)) + __popcll(__ballot(v1 == m1));
    float thr;
    if (c1 >= 3) {
      thr = m1;
    } else {
      float w0 = (v0 == m1) ? -INFINITY : v0;
      float w1 = (v1 == m1) ? -INFINITY : v1;
      const float m2 = wred_max(fmaxf(w0, w1));
      const int c2 = __popcll(__ballot(w0 == m2)) + __popcll(__ballot(w1 == m2));
      if (c1 + c2 >= 3) {
        thr = m2;
      } else {
        w0 = (w0 == m2) ? -INFINITY : w0;
        w1 = (w1 == m2) ? -INFINITY : w1;
        thr = wred_max(fmaxf(w0, w1));
      }
    }
    // ---- softmax over survivors + entropy pieces ----
    float ev0 = 0.f, ev1 = 0.f;
    float s0 = 0.f, s1 = 0.f, cnt = 0.f;
    if (v0 >= thr) {
      float e = expf(v0 - m1);
      if (e > 0.f) { ev0 = e; s0 += e; s1 += e * (v0 - m1); cnt += 1.f; }
    }
    if (v1 >= thr) {
      float e = expf(v1 - m1);
      if (e > 0.f) { ev1 = e; s0 += e; s1 += e * (v1 - m1); cnt += 1.f; }
    }
    s0 = wred_sum(s0);
    s1 = wred_sum(s1);
    cnt = wred_sum(cnt);
    float attn0 = 0.f, attn1 = 0.f, conf_h = 0.f;
    if (cnt > 0.f) {
      const float inv = 1.0f / s0;
      attn0 = ev0 * inv;
      attn1 = ev1 * inv;
      const float maxp = inv;
      const float teff = fmaxf(cnt, 2.0f);
      float entn = (logf(s0) - s1 * inv) + (77.0f - cnt) * 1.8420681e-7f;
      const float ent = fmaxf(entn / logf(teff), 0.0f);
      conf_h = fminf(fmaxf(maxp * (1.0f - ent), 0.0f), 1.0f);
    }
    // ---- ballot-compact sparse weights into wave-local lists ----
    unsigned long long m0 = __ballot(attn0 != 0.0f);
    unsigned long long m1b = __ballot(attn1 != 0.0f);
    const int c0n = __popcll(m0);
    if (attn0 != 0.0f) {
      const int rk = __popcll(m0 & lmask);
      s_lt[wv][hh][rk] = (short)lane;
      s_lw[wv][hh][rk] = attn0;
    }
    if (attn1 != 0.0f) {
      const int rk = c0n + __popcll(m1b & lmask);
      s_lt[wv][hh][rk] = (short)(64 + lane);
      s_lw[wv][hh][rk] = attn1;
    }
    if (lane == 0) {
      s_cnt[wv][hh] = c0n + __popcll(m1b);
      s_conf[h] = conf_h;
    }
  }
  __syncthreads();
  if (tid == 0) {
    float cm = 0.f;
#pragma unroll
    for (int h = 0; h < 8; ++h) cm += s_conf[h];
    cm *= 0.125f;
    cm = fminf(fmaxf(cm, 0.0f), 1.0f);
    conf_out[row] = 0.35f + 0.65f * cm;
  }
  // ---- sparse PV: wave covers its own 2 heads (128 channels, 2 per lane) ----
  {
    const int hsel = lane >> 5;
    const int h = wv * 2 + hsel;
    const int li = lane & 31;
    const int cnt = s_cnt[wv][hsel];
    float a0 = 0.f, a1 = 0.f;
    for (int i = 0; i < cnt; ++i) {
      const int t = s_lt[wv][hsel][i];
      const float w = s_lw[wv][hsel][i];
      const float2 vv = *(const float2*)(vf + (size_t)(b * 77 + t) * 512 + h * 64 + li * 2);
      a0 = fmaf(w, vv.x, a0);
      a1 = fmaf(w, vv.y, a1);
    }
    const unsigned int packed = (unsigned int)f2bf(a0) | ((unsigned int)f2bf(a1) << 16);
    *(unsigned int*)(alignedb + (size_t)row * 512 + h * 64 + li * 2) = packed;
  }
}

// ---------------- bf16 MFMA GEMM: out = epi(A[M,K] @ WT[N,K]^T + bias) --------
template <int EPI>
__global__ __launch_bounds__(256)
void mfma_gemm(const unsigned short* __restrict__ A,
               const unsigned short* __restrict__ WT,
               const float* __restrict__ bias,
               void* __restrict__ outv, int M, int N, int K,
               const unsigned short* __restrict__ e0b,
               const float* __restrict__ e1f,
               const float* __restrict__ e2f,
               const float* __restrict__ scf) {
  __shared__ __align__(16) unsigned short As[128 * 32];
  __shared__ __align__(16) unsigned short Bs[128 * 32];
  const int tid = threadIdx.x;
  const int wid = tid >> 6, lane = tid & 63;
  const int wr = wid >> 1, wc = wid & 1;
  const int m16 = lane & 15, quad = lane >> 4;
  const int row0 = blockIdx.y * 128, col0 = blockIdx.x * 128;

  const floatx4 zero4 = {0.f, 0.f, 0.f, 0.f};
  floatx4 acc[4][4];
#pragma unroll
  for (int i = 0; i < 4; ++i)
#pragma unroll
    for (int j = 0; j < 4; ++j) acc[i][j] = zero4;

  const unsigned short* Ag = A + (size_t)(row0 + (tid >> 2)) * K + (tid & 3) * 8;
  const unsigned short* Bg = WT + (size_t)(col0 + (tid >> 2)) * K + (tid & 3) * 8;
  char* AsB = (char*)As + tid * 16;
  char* BsB = (char*)Bs + tid * 16;
  const unsigned short* aP = As + (wr * 64 + m16) * 32 + quad * 8;
  const unsigned short* bP = Bs + (wc * 64 + m16) * 32 + quad * 8;

  for (int k0 = 0; k0 < K; k0 += 32) {
    __syncthreads();
    __builtin_amdgcn_global_load_lds(GPTR(Ag + k0), LPTR(AsB), 16, 0, 0);
    __builtin_amdgcn_global_load_lds(GPTR(Ag + (size_t)64 * K + k0), LPTR(AsB + 4096), 16, 0, 0);
    __builtin_amdgcn_global_load_lds(GPTR(Bg + k0), LPTR(BsB), 16, 0, 0);
    __builtin_amdgcn_global_load_lds(GPTR(Bg + (size_t)64 * K + k0), LPTR(BsB + 4096), 16, 0, 0);
    __syncthreads();
    bf16x8 af[4], bfr[4];
#pragma unroll
    for (int i = 0; i < 4; ++i) {
      af[i] = *(const bf16x8*)(aP + i * 16 * 32);
      bfr[i] = *(const bf16x8*)(bP + i * 16 * 32);
    }
#pragma unroll
    for (int mi = 0; mi < 4; ++mi)
#pragma unroll
      for (int ni = 0; ni < 4; ++ni)
        acc[mi][ni] = __builtin_amdgcn_mfma_f32_16x16x32_bf16(af[mi], bfr[ni], acc[mi][ni], 0, 0, 0);
  }

  float* outf = (float*)outv;
  unsigned short* outb = (unsigned short*)outv;
  float bb[4];
#pragma unroll
  for (int ni = 0; ni < 4; ++ni) bb[ni] = bias[col0 + wc * 64 + ni * 16 + m16];
  const float alphav = (EPI == 2) ? scf[0] : 0.f;

#pragma unroll
  for (int mi = 0; mi < 4; ++mi) {
#pragma unroll
    for (int r = 0; r < 4; ++r) {
      const int row = row0 + wr * 64 + mi * 16 + quad * 4 + r;
      float rowscale = 1.f, geo = 0.f;
      if (EPI == 1) rowscale = e1f[row];
      if (EPI == 2) geo = fminf(fmaxf(e2f[row], 0.3f), 1.0f);
#pragma unroll
      for (int ni = 0; ni < 4; ++ni) {
        const int col = col0 + wc * 64 + ni * 16 + m16;
        const size_t idx = (size_t)row * N + col;
        float o = acc[mi][ni][r] + bb[ni];
        if (EPI == 0) {
          outf[idx] = o;
        } else if (EPI == 1) {
          outf[idx] = o * rowscale;
        } else if (EPI == 2) {
          const float x = bf2f(e0b[idx]);
          const float al = e1f[idx];
          const float sg = 1.0f / (1.0f + expf(-o));
          outf[idx] = x + alphav * sg * geo * al;
        } else if (EPI == 3) {
          const float g = 0.5f * o * (1.0f + erff(o * 0.70710678118654752f));
          outb[idx] = f2bf(g);
        } else {
          outf[idx] = o + e1f[idx];
        }
      }
    }
  }
}

extern "C" void kernel_launch(void* const* d_in, const int* in_sizes, int n_in,
                              void* d_out, int out_size, void* d_ws, size_t ws_size,
                              hipStream_t stream) {
  const float* visual = (const float*)d_in[0];
  const float* text   = (const float*)d_in[1];
  const float* geo    = (const float*)d_in[2];
  const float* ln1_w  = (const float*)d_in[3];
  const float* ln1_b  = (const float*)d_in[4];
  const float* wq     = (const float*)d_in[5];
  const float* bq     = (const float*)d_in[6];
  const float* wk     = (const float*)d_in[7];
  const float* bk     = (const float*)d_in[8];
  const float* wvw    = (const float*)d_in[9];
  const float* bv     = (const float*)d_in[10];
  const float* wo     = (const float*)d_in[11];
  const float* bo     = (const float*)d_in[12];
  const float* gate_w = (const float*)d_in[13];
  const float* gate_b = (const float*)d_in[14];
  const float* logit_scale = (const float*)d_in[15];
  const float* alpha  = (const float*)d_in[16];
  const float* ln2_w  = (const float*)d_in[17];
  const float* ln2_b  = (const float*)d_in[18];
  const float* ffn_w1 = (const float*)d_in[19];
  const float* ffn_b1 = (const float*)d_in[20];
  const float* ffn_w2 = (const float*)d_in[21];
  const float* ffn_b2 = (const float*)d_in[22];
  float* out = (float*)d_out;

  char* ws = (char*)d_ws;
  // R0 (88 MB): q fp32 -> SIM fp32 -> alignedO fp32 -> GCH bf16
  float* R0            = (float*)ws;
  float* BUF2          = (float*)(ws + 88080384);             // y fp32, 64 MB
  unsigned short* Xb   = (unsigned short*)(ws + 155189248);   // 32 MB
  unsigned short* QNb  = (unsigned short*)(ws + 188743680);   // 32 MB (-> ALb later)
  unsigned short* wqT  = (unsigned short*)(ws + 222298112);
  unsigned short* woT  = wqT + 262144;
  unsigned short* gateT = woT + 262144;
  unsigned short* w1T  = gateT + 262144;                      // [2048,512]
  unsigned short* w2T  = w1T + 1048576;                       // [512,2048]
  unsigned short* KHb  = w2T + 1048576;                       // [64,80,64] bf16
  float* VF   = (float*)(ws + 228884480);                     // [616,512]
  float* PAD  = (float*)(ws + 230146048);                     // [616]
  float* CONF = (float*)(ws + 230148608);                     // [32768]

  float* Qf = R0;
  float* SIM = R0;
  float* AO = R0;
  unsigned short* ALb = QNb;   // aliased: QN dead after sim_kernel

  // weight transposes -> bf16 [N,K]
  transpose_bf16_kernel<<<dim3(16, 16), 256, 0, stream>>>(wq, wqT, 512, 512);
  transpose_bf16_kernel<<<dim3(16, 16), 256, 0, stream>>>(wo, woT, 512, 512);
  transpose_bf16_kernel<<<dim3(16, 16), 256, 0, stream>>>(gate_w, gateT, 512, 512);
  transpose_bf16_kernel<<<dim3(64, 16), 256, 0, stream>>>(ffn_w1, w1T, 512, 2048);
  transpose_bf16_kernel<<<dim3(16, 64), 256, 0, stream>>>(ffn_w2, w2T, 2048, 512);

  // 1. x = LN1(visual) -> bf16
  ln_bf16_kernel<<<MTOT / 4, 256, 0, stream>>>(visual, ln1_w, ln1_b, Xb);
  // 2. text projections (k bf16 head-major [.,80,64], pad rows zeroed)
  text_proj_kernel<<<8 * TT, 256, 0, stream>>>(text, wk, bk, wvw, bv, KHb, VF, PAD);
  kpad_zero_kernel<<<48, 256, 0, stream>>>(KHb);
  // 3. q = x @ wq + bq (fp32)
  mfma_gemm<0><<<dim3(4, 256), 256, 0, stream>>>(Xb, wqT, bq, Qf, MTOT, 512, 512,
                                                 nullptr, nullptr, nullptr, nullptr);
  // 4. qn = l2norm(q) * scale -> bf16
  qnorm_kernel<<<MTOT / 4, 256, 0, stream>>>(Qf, logit_scale, QNb);
  // 5. SIM = qn . k^T  (MFMA)   [overwrites Qf - dead]
  sim_kernel<<<dim3(32, 64), 256, 0, stream>>>(QNb, KHb, SIM);
  // 6. topk/softmax/conf/PV -> ALb (bf16, overlays QNb - dead), CONF
  attn_pv_kernel<<<MTOT, 256, 0, stream>>>(SIM, VF, PAD, ALb, CONF);
  // 7. alignedO = (aligned @ wo + bo) * conf -> AO fp32 (overlays SIM - dead)
  mfma_gemm<1><<<dim3(4, 256), 256, 0, stream>>>(ALb, woT, bo, AO, MTOT, 512, 512,
                                                 nullptr, CONF, nullptr, nullptr);
  // 8. y = x + alpha*sigmoid(x@gate_w+gate_b)*geo*alignedO -> BUF2
  mfma_gemm<2><<<dim3(4, 256), 256, 0, stream>>>(Xb, gateT, gate_b, BUF2, MTOT, 512, 512,
                                                 Xb, AO, geo, alpha);
  // 9. h = LN2(y) -> Xb (bf16)
  ln_bf16_kernel<<<MTOT / 4, 256, 0, stream>>>(BUF2, ln2_w, ln2_b, Xb);
  // 10. FFN in 2 chunks of 16384 rows; GCH (bf16) overlays R0 (AO dead)
  unsigned short* GCH = (unsigned short*)R0;
  for (int ch = 0; ch < 2; ++ch) {
    const size_t off = (size_t)ch * 16384;
    mfma_gemm<3><<<dim3(16, 128), 256, 0, stream>>>(Xb + off * 512, w1T, ffn_b1, GCH,
                                                    16384, 2048, 512,
                                                    nullptr, nullptr, nullptr, nullptr);
    mfma_gemm<4><<<dim3(4, 128), 256, 0, stream>>>(GCH, w2T, ffn_b2, out + off * 512,
                                                   16384, 512, 2048,
                                                   nullptr, BUF2 + off * 512, nullptr, nullptr);
  }
}